// Round 1
// baseline (4221.902 us; speedup 1.0000x reference)
//
#include <hip/hip_runtime.h>
#include <stdint.h>

#define N_POINTS  400000
#define WIDTH     64
#define M_SAMPLES 1000          // N_POINTS / 400
#define NBLK      64
#define NTHR      256
#define NW        (NTHR / 64)   // 4 waves per block
#define NSLOT     (NBLK * NW)   // 256 candidate entries per buffer
#define NTOT      (NBLK * NTHR) // 16384 threads
#define PPT       25            // ceil(400000 / 16384)
#define TAIL_GID  (N_POINTS - (PPT - 1) * NTOT)  // 6784: gid < this => k=24 valid
#define EWORDS    4             // entry = {key, x, y, z} as 4 u64 words (32 B)
#define BUFWORDS  (NSLOT * EWORDS)

// Entry word formats (per-word self-validating, 2-bit tag = i & 3):
//   key : [63:32] dist f32 bits (sign always 0) | [20:19] tag | [18:0] N - idx
//   x/y/z: [63:32] coord f32 bits | [1:0] tag
// Double-buffered by (i & 1); same-buffer stale entries are from i-2 whose tag
// differs in bit 1, so mod-4 tags fully disambiguate. Structurally no block can
// overwrite an entry another block still needs: storing i+2 requires gathering
// i+1, which requires every block to have stored i+1, i.e. finished gathering i.

__global__ void fps_init(unsigned long long* slot, int* out) {
    int t = blockIdx.x * blockDim.x + threadIdx.x;
    if (t < 2 * BUFWORDS) slot[t] = 0ull;   // tag 0 => invalid for i=1..3; overwritten by i=4
    if (t == 0) out[0] = 0;                 // seed index
}

// 64-lane u64 max-reduce via DPP scan (row_shr 1/2/4/8 + row_bcast15/31),
// result broadcast wave-uniform via readlane(63). ~100 cy vs ~300-700 for a
// ds_bpermute butterfly. bound_ctrl=false => invalid lanes keep old (max no-op).
__device__ inline unsigned long long wave_max_u64(unsigned long long key) {
    unsigned int lo = (unsigned int)key;
    unsigned int hi = (unsigned int)(key >> 32);
#define FPS_DPP_STAGE(CTRL)                                                     \
    {                                                                           \
        unsigned int nlo = (unsigned int)__builtin_amdgcn_update_dpp(           \
            (int)lo, (int)lo, CTRL, 0xf, 0xf, false);                           \
        unsigned int nhi = (unsigned int)__builtin_amdgcn_update_dpp(           \
            (int)hi, (int)hi, CTRL, 0xf, 0xf, false);                           \
        unsigned long long cand = ((unsigned long long)nhi << 32) | nlo;        \
        unsigned long long cur  = ((unsigned long long)hi  << 32) | lo;         \
        if (cand > cur) { lo = nlo; hi = nhi; }                                 \
    }
    FPS_DPP_STAGE(0x111)  // row_shr:1
    FPS_DPP_STAGE(0x112)  // row_shr:2
    FPS_DPP_STAGE(0x114)  // row_shr:4
    FPS_DPP_STAGE(0x118)  // row_shr:8   -> lane15 of each row = row max
    FPS_DPP_STAGE(0x142)  // row_bcast15 -> lane31/63 = pair max
    FPS_DPP_STAGE(0x143)  // row_bcast31 -> lane63 = wave max
#undef FPS_DPP_STAGE
    unsigned int rlo = (unsigned int)__builtin_amdgcn_readlane((int)lo, 63);
    unsigned int rhi = (unsigned int)__builtin_amdgcn_readlane((int)hi, 63);
    return ((unsigned long long)rhi << 32) | rlo;
}

// Workspace requirement: 2 * BUFWORDS * 8 B = 16 KiB in d_ws.
__global__ __launch_bounds__(NTHR)
void fps_main(const float* __restrict__ feats, int* __restrict__ out,
              unsigned long long* __restrict__ slot)
{
    const int tid  = threadIdx.x;
    const int bid  = blockIdx.x;
    const int lane = tid & 63;
    const int wid  = tid >> 6;
    const int gid  = bid * NTHR + tid;

    // Register-resident points + running min squared distance
    float px[PPT], py[PPT], pz[PPT], dd[PPT];
#pragma unroll
    for (int k = 0; k < PPT; k++) {
        int j = gid + k * NTOT;
        if (j < N_POINTS) {
            px[k] = feats[(size_t)j * WIDTH + 0];
            py[k] = feats[(size_t)j * WIDTH + 1];
            pz[k] = feats[(size_t)j * WIDTH + 2];
        } else {
            px[k] = 0.f; py[k] = 0.f; pz[k] = 0.f;
        }
        dd[k] = 1e10f;          // matches jnp.full(..., 1e10, f32)
    }

    __shared__ float s_qx, s_qy, s_qz;

    // Iteration-1 pivot = point 0 (bit-identical source values)
    float qx = feats[0];
    float qy = feats[1];
    float qz = feats[2];

    for (int i = 1; i < M_SAMPLES; i++) {
        const unsigned long long tagll = (unsigned long long)(i & 3);
        unsigned long long* buf = slot + (size_t)(i & 1) * BUFWORDS;

        // ---- compute pass: update dd, track per-thread best (dist,idx,xyz) ----
        float bd = -1.0f, bx = 0.f, by = 0.f, bz = 0.f;
        unsigned int bj = 0;
#pragma unroll
        for (int k = 0; k < PPT; k++) {
            int j = gid + k * NTOT;
            // IEEE ops in reference order; _rn intrinsics block fp-contract
            float dx = __fsub_rn(px[k], qx);
            float dy = __fsub_rn(py[k], qy);
            float dz = __fsub_rn(pz[k], qz);
            float d  = __fadd_rn(__fadd_rn(__fmul_rn(dx, dx), __fmul_rn(dy, dy)),
                                 __fmul_rn(dz, dz));
            float nd = fminf(dd[k], d);
            dd[k] = nd;
            bool upd = (nd > bd);                 // strict > keeps smallest j on ties
            if (k == PPT - 1) upd = upd && (gid < TAIL_GID);
            bd = upd ? nd : bd;
            bj = upd ? (unsigned int)j : bj;
            bx = upd ? px[k] : bx;
            by = upd ? py[k] : by;
            bz = upd ? pz[k] : bz;
        }
        // key: dist bits high, tag, (N - idx) low (19 bits) => max key = max
        // dist, ties -> lowest idx. Same-tag keys compare exactly as before.
        unsigned long long key =
            ((unsigned long long)__float_as_uint(bd) << 32) |
            (tagll << 19) |
            (unsigned long long)(N_POINTS - bj);

        // ---- wave reduce (DPP) + winner-lane xyz extraction ----
        unsigned long long win1 = wave_max_u64(key);   // wave-uniform
        unsigned long long m1   = __ballot(key == win1);
        int src1 = (int)__builtin_ctzll(m1);           // keys distinct: one bit
        float wx = __shfl(bx, src1, 64);
        float wy = __shfl(by, src1, 64);
        float wz = __shfl(bz, src1, 64);

        if (lane == 0) {
            unsigned long long* e = buf + (size_t)(bid * NW + wid) * EWORDS;
            __hip_atomic_store(e + 0, win1,
                               __ATOMIC_RELAXED, __HIP_MEMORY_SCOPE_AGENT);
            __hip_atomic_store(e + 1,
                ((unsigned long long)__float_as_uint(wx) << 32) | tagll,
                __ATOMIC_RELAXED, __HIP_MEMORY_SCOPE_AGENT);
            __hip_atomic_store(e + 2,
                ((unsigned long long)__float_as_uint(wy) << 32) | tagll,
                __ATOMIC_RELAXED, __HIP_MEMORY_SCOPE_AGENT);
            __hip_atomic_store(e + 3,
                ((unsigned long long)__float_as_uint(wz) << 32) | tagll,
                __ATOMIC_RELAXED, __HIP_MEMORY_SCOPE_AGENT);
        }

        if (wid == 0) {
            // Lane l gathers entries 4l..4l+3 (128 B contiguous per lane).
            const unsigned long long* pb = buf + (size_t)lane * 4 * EWORDS;
            bool ok0 = false, ok1 = false, ok2 = false, ok3 = false;
            unsigned long long k0=0,x0=0,y0=0,z0=0, k1=0,x1=0,y1=0,z1=0,
                               k2=0,x2=0,y2=0,z2=0, k3=0,x3=0,y3=0,z3=0;
#define FPS_POLL(E)                                                              \
            if (!ok##E) {                                                        \
                unsigned long long w0 = __hip_atomic_load(pb + E * EWORDS + 0,   \
                    __ATOMIC_RELAXED, __HIP_MEMORY_SCOPE_AGENT);                 \
                unsigned long long w1 = __hip_atomic_load(pb + E * EWORDS + 1,   \
                    __ATOMIC_RELAXED, __HIP_MEMORY_SCOPE_AGENT);                 \
                unsigned long long w2 = __hip_atomic_load(pb + E * EWORDS + 2,   \
                    __ATOMIC_RELAXED, __HIP_MEMORY_SCOPE_AGENT);                 \
                unsigned long long w3 = __hip_atomic_load(pb + E * EWORDS + 3,   \
                    __ATOMIC_RELAXED, __HIP_MEMORY_SCOPE_AGENT);                 \
                bool g = (((w0 >> 19) & 3ull) == tagll) &                        \
                         ((w1 & 3ull) == tagll) &                                \
                         ((w2 & 3ull) == tagll) &                                \
                         ((w3 & 3ull) == tagll);                                 \
                if (g) { k##E = w0; x##E = w1; y##E = w2; z##E = w3;             \
                         ok##E = true; }                                         \
            }
            do {
                FPS_POLL(0) FPS_POLL(1) FPS_POLL(2) FPS_POLL(3)
            } while (!(ok0 & ok1 & ok2 & ok3));
#undef FPS_POLL

            // local max of 4 entries, carrying payload
            unsigned long long bk = k0, pxw = x0, pyw = y0, pzw = z0;
            if (k1 > bk) { bk = k1; pxw = x1; pyw = y1; pzw = z1; }
            if (k2 > bk) { bk = k2; pxw = x2; pyw = y2; pzw = z2; }
            if (k3 > bk) { bk = k3; pxw = x3; pyw = y3; pzw = z3; }

            unsigned long long win = wave_max_u64(bk);     // wave-uniform
            unsigned long long mm  = __ballot(bk == win);
            int src = (int)__builtin_ctzll(mm);
            unsigned int xb = (unsigned int)__shfl((int)(unsigned int)(pxw >> 32), src, 64);
            unsigned int yb = (unsigned int)__shfl((int)(unsigned int)(pyw >> 32), src, 64);
            unsigned int zb = (unsigned int)__shfl((int)(unsigned int)(pzw >> 32), src, 64);

            if (lane == 0) {
                s_qx = __uint_as_float(xb);
                s_qy = __uint_as_float(yb);
                s_qz = __uint_as_float(zb);
                if (bid == 0)
                    out[i] = (int)(N_POINTS - (unsigned int)(win & 0x7FFFFull));
            }
        }
        // Single barrier: waves 1-3 arrive right after their store; wave 0
        // releases once s_q* is written. Waves 1-3 are guaranteed to read s_q*
        // before wave 0's next overwrite (wave 0's next gather needs their next
        // stores, which follow their reads).
        __syncthreads();
        qx = s_qx; qy = s_qy; qz = s_qz;
    }
}

extern "C" void kernel_launch(void* const* d_in, const int* in_sizes, int n_in,
                              void* d_out, int out_size, void* d_ws, size_t ws_size,
                              hipStream_t stream) {
    const float* feats = (const float*)d_in[0];
    int* out = (int*)d_out;
    unsigned long long* slot = (unsigned long long*)d_ws;  // 16 KiB used

    fps_init<<<(2 * BUFWORDS + 255) / 256, 256, 0, stream>>>(slot, out);
    // 64 blocks x 256 thr: well under 256 CUs -> all blocks resident
    fps_main<<<NBLK, NTHR, 0, stream>>>(feats, out, slot);
}

// Round 3
// 3412.969 us; speedup vs baseline: 1.2370x; 1.2370x over previous
//
#include <hip/hip_runtime.h>
#include <stdint.h>

#define N_POINTS  400000
#define WIDTH     64
#define M_SAMPLES 1000          // N_POINTS / 400
#define NBLK      64
#define NTHR      256
#define NW        (NTHR / 64)   // 4 waves per block
#define NSLOT     (NBLK * NW)   // 256 candidate entries per buffer
#define NTOT      (NBLK * NTHR) // 16384 threads
#define PPT       25            // ceil(400000 / 16384)
#define TAIL_GID  (N_POINTS - (PPT - 1) * NTOT)  // 6784: gid < this => k=24 valid

// Single-word entry (the ONE thing on the fabric):
//   [63:32] dist f32 bits (non-negative -> monotone u32)
//   [20:19] tag = i & 3
//   [18:0]  N - idx  (1..400000, nonzero, fits 19 bits; ties -> lowest idx wins)
// Double-buffered by (i & 1). Stale same-buffer entries are from i-2 whose tag
// differs in bit 1 -> mod-4 tags fully disambiguate. Overwrite-safety: a block
// stores i+2 only after gathering i+1, which requires all blocks stored i+1,
// which requires every block finished gathering i. Read-read coherence on a
// single location means a poller can never re-observe an older value after
// seeing a newer one. (Protocol HW-verified rounds 0/1: absmax 0. Round 2's
// failure was ONLY the init under-launch: 256 threads zeroing 512 words.)

__global__ void fps_init(unsigned long long* slot, int* out) {
    int t = blockIdx.x * blockDim.x + threadIdx.x;
    if (t < 2 * NSLOT) slot[t] = 0ull;   // tag 0 = invalid for i=1..3
    if (t == 0) out[0] = 0;              // seed index
}

// 64-lane u64 max-reduce via DPP scan (row_shr 1/2/4/8 + row_bcast15/31),
// result broadcast wave-uniform via readlane(63). ~100 cy vs ~300-500 for a
// ds-pipe butterfly. bound_ctrl=false => invalid lanes keep old (max no-op).
// HW-verified on gfx950 in round 1 (passed correctness with this exact code).
__device__ inline unsigned long long wave_max_u64(unsigned long long key) {
    unsigned int lo = (unsigned int)key;
    unsigned int hi = (unsigned int)(key >> 32);
#define FPS_DPP_STAGE(CTRL)                                                     \
    {                                                                           \
        unsigned int nlo = (unsigned int)__builtin_amdgcn_update_dpp(           \
            (int)lo, (int)lo, CTRL, 0xf, 0xf, false);                           \
        unsigned int nhi = (unsigned int)__builtin_amdgcn_update_dpp(           \
            (int)hi, (int)hi, CTRL, 0xf, 0xf, false);                           \
        unsigned long long cand = ((unsigned long long)nhi << 32) | nlo;        \
        unsigned long long cur  = ((unsigned long long)hi  << 32) | lo;         \
        if (cand > cur) { lo = nlo; hi = nhi; }                                 \
    }
    FPS_DPP_STAGE(0x111)  // row_shr:1
    FPS_DPP_STAGE(0x112)  // row_shr:2
    FPS_DPP_STAGE(0x114)  // row_shr:4
    FPS_DPP_STAGE(0x118)  // row_shr:8   -> lane15 of each row = row max
    FPS_DPP_STAGE(0x142)  // row_bcast15 -> lane31/63 = pair max
    FPS_DPP_STAGE(0x143)  // row_bcast31 -> lane63 = wave max
#undef FPS_DPP_STAGE
    unsigned int rlo = (unsigned int)__builtin_amdgcn_readlane((int)lo, 63);
    unsigned int rhi = (unsigned int)__builtin_amdgcn_readlane((int)hi, 63);
    return ((unsigned long long)rhi << 32) | rlo;
}

// Workspace requirement: 2 * NSLOT * 8 B = 4 KiB in d_ws.
__global__ __launch_bounds__(NTHR)
void fps_main(const float* __restrict__ feats, int* __restrict__ out,
              unsigned long long* __restrict__ slot)
{
    const int tid  = threadIdx.x;
    const int bid  = blockIdx.x;
    const int lane = tid & 63;
    const int wid  = tid >> 6;
    const int gid  = bid * NTHR + tid;

    // Register-resident points + running min squared distance
    float px[PPT], py[PPT], pz[PPT], dd[PPT];
#pragma unroll
    for (int k = 0; k < PPT; k++) {
        int j = gid + k * NTOT;
        if (j < N_POINTS) {
            px[k] = feats[(size_t)j * WIDTH + 0];
            py[k] = feats[(size_t)j * WIDTH + 1];
            pz[k] = feats[(size_t)j * WIDTH + 2];
        } else {
            px[k] = 0.f; py[k] = 0.f; pz[k] = 0.f;
        }
        dd[k] = 1e10f;          // matches jnp.full(..., 1e10, f32)
    }

    __shared__ unsigned long long s_key;

    int last = 0;
    for (int i = 1; i < M_SAMPLES; i++) {
        const unsigned long long tagll = (unsigned long long)(i & 3);
        unsigned long long* buf = slot + (size_t)(i & 1) * NSLOT;

        // Pivot coords (same address across lanes -> one broadcast transaction)
        float qx = feats[(size_t)last * WIDTH + 0];
        float qy = feats[(size_t)last * WIDTH + 1];
        float qz = feats[(size_t)last * WIDTH + 2];

        // ---- compute pass: update dd, float-track per-thread best (dist,idx) ----
        float bd = -1.0f;
        unsigned int bj = 0;
#pragma unroll
        for (int k = 0; k < PPT; k++) {
            int j = gid + k * NTOT;
            // IEEE ops in reference order; _rn intrinsics block fp-contract
            float dx = __fsub_rn(px[k], qx);
            float dy = __fsub_rn(py[k], qy);
            float dz = __fsub_rn(pz[k], qz);
            float d  = __fadd_rn(__fadd_rn(__fmul_rn(dx, dx), __fmul_rn(dy, dy)),
                                 __fmul_rn(dz, dz));
            float nd = fminf(dd[k], d);
            dd[k] = nd;
            // strict > keeps the smallest j on ties (j ascends with k)
            bool upd = (nd > bd);
            if (k == PPT - 1) upd = upd && (gid < TAIL_GID);
            bd = upd ? nd : bd;
            bj = upd ? (unsigned int)j : bj;
        }
        // Build the u64 key ONCE per iteration (not per point)
        unsigned long long key =
            ((unsigned long long)__float_as_uint(bd) << 32) |
            (tagll << 19) |
            (unsigned long long)(N_POINTS - bj);

        // ---- wave reduce (DPP, wave-uniform result) + per-wave store ----
        unsigned long long best = wave_max_u64(key);
        if (lane == 0) {
            __hip_atomic_store(&buf[bid * NW + wid], best,
                               __ATOMIC_RELAXED, __HIP_MEMORY_SCOPE_AGENT);
        }

        if (wid == 0) {
            // Lane l polls the 4 entries of block l (contiguous 32 B).
            const unsigned long long* sl = buf + (size_t)lane * NW;
            unsigned long long k0 = 0, k1 = 0, k2 = 0, k3 = 0;
            bool ok0 = false, ok1 = false, ok2 = false, ok3 = false;
#define FPS_POLL(E)                                                              \
            if (!ok##E) {                                                        \
                unsigned long long w = __hip_atomic_load(sl + E,                 \
                    __ATOMIC_RELAXED, __HIP_MEMORY_SCOPE_AGENT);                 \
                if (((w >> 19) & 3ull) == tagll) { k##E = w; ok##E = true; }     \
            }
            do {
                FPS_POLL(0) FPS_POLL(1) FPS_POLL(2) FPS_POLL(3)
            } while (!(ok0 & ok1 & ok2 & ok3));
#undef FPS_POLL

            unsigned long long v = k0;
            if (k1 > v) v = k1;
            if (k2 > v) v = k2;
            if (k3 > v) v = k3;
            unsigned long long win = wave_max_u64(v);   // wave-uniform
            if (lane == 0) {
                s_key = win;
                if (bid == 0)
                    out[i] = (int)(N_POINTS - (unsigned int)(win & 0x7FFFFull));
            }
        }
        // Single barrier: waves 1-3 arrive right after their store; wave 0
        // releases it once s_key is written.
        __syncthreads();
        last = (int)(N_POINTS - (unsigned int)(s_key & 0x7FFFFull));
    }
}

extern "C" void kernel_launch(void* const* d_in, const int* in_sizes, int n_in,
                              void* d_out, int out_size, void* d_ws, size_t ws_size,
                              hipStream_t stream) {
    const float* feats = (const float*)d_in[0];
    int* out = (int*)d_out;
    unsigned long long* slot = (unsigned long long*)d_ws;  // 4 KiB used

    // 512 threads: must cover 2 * NSLOT = 512 words (round-2 bug: was 1 block)
    fps_init<<<2, 256, 0, stream>>>(slot, out);
    // 64 blocks x 256 thr: well under 256 CUs -> all blocks resident
    fps_main<<<NBLK, NTHR, 0, stream>>>(feats, out, slot);
}

// Round 4
// 3259.772 us; speedup vs baseline: 1.2952x; 1.0470x over previous
//
#include <hip/hip_runtime.h>
#include <stdint.h>

#define N_POINTS   400000
#define WIDTH      64
#define M_SAMPLES  1000          // N_POINTS / 400
#define NBLK       32
#define NTHR       512
#define NWAVE      (NTHR / 64)   // 8 waves per block
#define NTOT       (NBLK * NTHR) // 16384 threads (same as prior rounds)
#define PPT        25            // ceil(400000 / 16384)
#define TAIL_GID   (N_POINTS - (PPT - 1) * NTOT)  // 6784: gid < this => k=24 valid
#define SLOT_WORDS ((M_SAMPLES - 1) * NBLK)       // 31968 words = ~250 KB

// Entry (single 8-B word, fresh region per iteration -> poll predicate != 0):
//   [63:32] dist f32 bits (non-negative -> monotone u32)
//   [31:0]  N - idx  (1..400000, always nonzero; ties -> lowest idx wins)
// Fresh-region-per-iteration replicates round 0's comm pattern (measured
// faster than hot-line reuse in round 3: 2971 vs 3287 us) and needs no tags.

__global__ void fps_init(unsigned long long* slot, int* out) {
    int t = blockIdx.x * blockDim.x + threadIdx.x;
    if (t < SLOT_WORDS) slot[t] = 0ull;
    if (t == 0) out[0] = 0;      // seed index
}

// u64 max-reduce over the first 2^STAGES-ish lanes via DPP row-scan.
// STAGES=3 + SRC=7  : max over lanes 0..7   (block-level, 8 wave maxima)
// STAGES=5 + SRC=31 : max over lanes 0..31  (global, 32 block entries)
// STAGES=6 + SRC=63 : max over all 64 lanes (per-wave candidate reduce)
// bound_ctrl=false => out-of-row lanes keep old value (max no-op).
// (DPP u64-max scan HW-verified on gfx950 in rounds 1/3.)
template <int STAGES, int SRCLANE>
__device__ inline unsigned long long wave_scan_max_u64(unsigned long long key) {
    unsigned int lo = (unsigned int)key;
    unsigned int hi = (unsigned int)(key >> 32);
#define FPS_DPP_STAGE(CTRL)                                                     \
    {                                                                           \
        unsigned int nlo = (unsigned int)__builtin_amdgcn_update_dpp(           \
            (int)lo, (int)lo, CTRL, 0xf, 0xf, false);                           \
        unsigned int nhi = (unsigned int)__builtin_amdgcn_update_dpp(           \
            (int)hi, (int)hi, CTRL, 0xf, 0xf, false);                           \
        unsigned long long cand = ((unsigned long long)nhi << 32) | nlo;        \
        unsigned long long cur  = ((unsigned long long)hi  << 32) | lo;         \
        if (cand > cur) { lo = nlo; hi = nhi; }                                 \
    }
    if constexpr (STAGES > 0) FPS_DPP_STAGE(0x111)  // row_shr:1
    if constexpr (STAGES > 1) FPS_DPP_STAGE(0x112)  // row_shr:2
    if constexpr (STAGES > 2) FPS_DPP_STAGE(0x114)  // row_shr:4
    if constexpr (STAGES > 3) FPS_DPP_STAGE(0x118)  // row_shr:8   -> lane15 = row max
    if constexpr (STAGES > 4) FPS_DPP_STAGE(0x142)  // row_bcast15 -> lane31 = max(0..31)
    if constexpr (STAGES > 5) FPS_DPP_STAGE(0x143)  // row_bcast31 -> lane63 = max(0..63)
#undef FPS_DPP_STAGE
    unsigned int rlo = (unsigned int)__builtin_amdgcn_readlane((int)lo, SRCLANE);
    unsigned int rhi = (unsigned int)__builtin_amdgcn_readlane((int)hi, SRCLANE);
    return ((unsigned long long)rhi << 32) | rlo;
}

// Workspace requirement: SLOT_WORDS * 8 B = 255,744 B in d_ws.
__global__ __launch_bounds__(NTHR)
void fps_main(const float* __restrict__ feats, int* __restrict__ out,
              unsigned long long* __restrict__ slot)
{
    const int tid  = threadIdx.x;
    const int bid  = blockIdx.x;
    const int lane = tid & 63;
    const int wid  = tid >> 6;
    const int gid  = bid * NTHR + tid;

    // Register-resident points + running min squared distance
    float px[PPT], py[PPT], pz[PPT], dd[PPT];
#pragma unroll
    for (int k = 0; k < PPT; k++) {
        int j = gid + k * NTOT;
        if (j < N_POINTS) {
            // row start is 256-B aligned -> one dwordx4 gets x,y,z(,w)
            float4 v = *reinterpret_cast<const float4*>(feats + (size_t)j * WIDTH);
            px[k] = v.x; py[k] = v.y; pz[k] = v.z;
        } else {
            px[k] = 0.f; py[k] = 0.f; pz[k] = 0.f;
        }
        dd[k] = 1e10f;          // matches jnp.full(..., 1e10, f32)
    }

    __shared__ unsigned long long s_wmax[NWAVE];
    __shared__ float s_qx, s_qy, s_qz;

    // Iteration-1 pivot = point 0 (bit-identical source values)
    float qx = feats[0];
    float qy = feats[1];
    float qz = feats[2];

    for (int i = 1; i < M_SAMPLES; i++) {
        // ---- compute pass: update dd, float-track per-thread best (dist,idx) ----
        float bd = -1.0f;
        unsigned int bj = 0;
#pragma unroll
        for (int k = 0; k < PPT; k++) {
            int j = gid + k * NTOT;
            // IEEE ops in reference order; _rn intrinsics block fp-contract
            float dx = __fsub_rn(px[k], qx);
            float dy = __fsub_rn(py[k], qy);
            float dz = __fsub_rn(pz[k], qz);
            float d  = __fadd_rn(__fadd_rn(__fmul_rn(dx, dx), __fmul_rn(dy, dy)),
                                 __fmul_rn(dz, dz));
            float nd = fminf(dd[k], d);
            dd[k] = nd;
            // strict > keeps the smallest j on ties (j ascends with k)
            bool upd = (nd > bd);
            if (k == PPT - 1) upd = upd && (gid < TAIL_GID);
            bd = upd ? nd : bd;
            bj = upd ? (unsigned int)j : bj;
        }
        unsigned long long key =
            ((unsigned long long)__float_as_uint(bd) << 32) |
            (unsigned long long)(unsigned int)(N_POINTS - bj);

        // ---- per-wave reduce, stage into LDS ----
        unsigned long long wmax = wave_scan_max_u64<6, 63>(key);
        if (lane == 0) s_wmax[wid] = wmax;
        __syncthreads();

        if (wid == 0) {
            // ---- block-level reduce: 8 wave maxima -> 1 entry, ONE store ----
            unsigned long long bk = (lane < NWAVE) ? s_wmax[lane] : 0ull;
            unsigned long long blockmax = wave_scan_max_u64<3, 7>(bk);
            unsigned long long* cur = slot + (size_t)(i - 1) * NBLK;
            if (lane == 0)
                __hip_atomic_store(&cur[bid], blockmax,
                                   __ATOMIC_RELAXED, __HIP_MEMORY_SCOPE_AGENT);

            // ---- poll: lane l (<32) waits on entry l (4 cache lines total) ----
            unsigned long long e = 0ull;
            if (lane < NBLK) {
                do {
                    e = __hip_atomic_load(&cur[lane], __ATOMIC_RELAXED,
                                          __HIP_MEMORY_SCOPE_AGENT);
                } while (e == 0ull);
            }

            // ---- speculative pivot fetch: each lane loads ITS candidate's row
            //      (issues immediately; latency overlaps the final reduce) ----
            unsigned int widx = 0;
            float4 pv = make_float4(0.f, 0.f, 0.f, 0.f);
            if (lane < NBLK) {
                widx = N_POINTS - (unsigned int)(e & 0xffffffffull);
                pv = *reinterpret_cast<const float4*>(feats + (size_t)widx * WIDTH);
            }

            unsigned long long win =
                wave_scan_max_u64<5, 31>((lane < NBLK) ? e : 0ull);

            // Exactly one lane matches (block candidates have distinct indices)
            if (lane < NBLK && e == win) {
                s_qx = pv.x; s_qy = pv.y; s_qz = pv.z;
                if (bid == 0) out[i] = (int)widx;
            }
        }
        // Waves 1..7 idle here while wave 0 runs the exchange
        __syncthreads();
        qx = s_qx; qy = s_qy; qz = s_qz;
    }
}

extern "C" void kernel_launch(void* const* d_in, const int* in_sizes, int n_in,
                              void* d_out, int out_size, void* d_ws, size_t ws_size,
                              hipStream_t stream) {
    const float* feats = (const float*)d_in[0];
    int* out = (int*)d_out;
    unsigned long long* slot = (unsigned long long*)d_ws;  // ~250 KiB used

    fps_init<<<(SLOT_WORDS + 255) / 256, 256, 0, stream>>>(slot, out);
    // 32 blocks x 512 thr: 32 CUs busy, all blocks trivially co-resident
    fps_main<<<NBLK, NTHR, 0, stream>>>(feats, out, slot);
}

// Round 5
// 2702.821 us; speedup vs baseline: 1.5620x; 1.2061x over previous
//
#include <hip/hip_runtime.h>
#include <stdint.h>

#define N_POINTS   400000
#define WIDTH      64
#define M_SAMPLES  1000          // N_POINTS / 400
#define NBLK       32
#define NTHR       512
#define NWAVE      (NTHR / 64)   // 8 waves per block
#define NTOT       (NBLK * NTHR) // 16384 threads
#define PPT        25            // ceil(400000 / 16384)
#define TAIL_GID   (N_POINTS - (PPT - 1) * NTOT)  // 6784: gid < this => k=24 valid
#define EPAD       8             // entry stride in u64 words = 64 B = ONE cache line
#define SLOT_WORDS ((M_SAMPLES - 1) * NBLK * EPAD) // 255,744 words = 2.046 MB

// Entry (single 8-B word at the head of a PRIVATE 64-B line):
//   [63:32] dist f32 bits (non-negative -> monotone u32)
//   [31:0]  N - idx  (1..400000, always nonzero; ties -> lowest idx wins)
// One writer per cache line: no write-write ownership serialization on the
// fabric. Fresh region per iteration -> poll predicate is simply != 0.

__global__ void fps_init(unsigned long long* slot, int* out) {
    int t = blockIdx.x * blockDim.x + threadIdx.x;
    if (t < SLOT_WORDS) slot[t] = 0ull;
    if (t == 0) out[0] = 0;      // seed index
}

// u64 max-reduce over lanes via DPP row-scan (HW-verified rounds 1/3/4).
// STAGES=3 + SRC=7  : max over lanes 0..7   (block-level, 8 wave maxima)
// STAGES=5 + SRC=31 : max over lanes 0..31  (global, 32 block entries)
// STAGES=6 + SRC=63 : max over all 64 lanes (per-wave candidate reduce)
template <int STAGES, int SRCLANE>
__device__ inline unsigned long long wave_scan_max_u64(unsigned long long key) {
    unsigned int lo = (unsigned int)key;
    unsigned int hi = (unsigned int)(key >> 32);
#define FPS_DPP_STAGE(CTRL)                                                     \
    {                                                                           \
        unsigned int nlo = (unsigned int)__builtin_amdgcn_update_dpp(           \
            (int)lo, (int)lo, CTRL, 0xf, 0xf, false);                           \
        unsigned int nhi = (unsigned int)__builtin_amdgcn_update_dpp(           \
            (int)hi, (int)hi, CTRL, 0xf, 0xf, false);                           \
        unsigned long long cand = ((unsigned long long)nhi << 32) | nlo;        \
        unsigned long long cur  = ((unsigned long long)hi  << 32) | lo;         \
        if (cand > cur) { lo = nlo; hi = nhi; }                                 \
    }
    if constexpr (STAGES > 0) FPS_DPP_STAGE(0x111)  // row_shr:1
    if constexpr (STAGES > 1) FPS_DPP_STAGE(0x112)  // row_shr:2
    if constexpr (STAGES > 2) FPS_DPP_STAGE(0x114)  // row_shr:4
    if constexpr (STAGES > 3) FPS_DPP_STAGE(0x118)  // row_shr:8   -> lane15 = row max
    if constexpr (STAGES > 4) FPS_DPP_STAGE(0x142)  // row_bcast15 -> lane31 = max(0..31)
    if constexpr (STAGES > 5) FPS_DPP_STAGE(0x143)  // row_bcast31 -> lane63 = max(0..63)
#undef FPS_DPP_STAGE
    unsigned int rlo = (unsigned int)__builtin_amdgcn_readlane((int)lo, SRCLANE);
    unsigned int rhi = (unsigned int)__builtin_amdgcn_readlane((int)hi, SRCLANE);
    return ((unsigned long long)rhi << 32) | rlo;
}

// Workspace requirement: SLOT_WORDS * 8 B = 2,045,952 B in d_ws.
__global__ __launch_bounds__(NTHR)
void fps_main(const float* __restrict__ feats, int* __restrict__ out,
              unsigned long long* __restrict__ slot)
{
    const int tid  = threadIdx.x;
    const int bid  = blockIdx.x;
    const int lane = tid & 63;
    const int wid  = tid >> 6;
    const int gid  = bid * NTHR + tid;

    // Register-resident points + running min squared distance
    float px[PPT], py[PPT], pz[PPT], dd[PPT];
#pragma unroll
    for (int k = 0; k < PPT; k++) {
        int j = gid + k * NTOT;
        if (j < N_POINTS) {
            // row start is 256-B aligned -> one dwordx4 gets x,y,z(,w)
            float4 v = *reinterpret_cast<const float4*>(feats + (size_t)j * WIDTH);
            px[k] = v.x; py[k] = v.y; pz[k] = v.z;
        } else {
            px[k] = 0.f; py[k] = 0.f; pz[k] = 0.f;
        }
        dd[k] = 1e10f;          // matches jnp.full(..., 1e10, f32)
    }

    __shared__ unsigned long long s_wmax[NWAVE];
    __shared__ float s_qx, s_qy, s_qz;

    // Iteration-1 pivot = point 0 (bit-identical source values)
    float qx = feats[0];
    float qy = feats[1];
    float qz = feats[2];

    for (int i = 1; i < M_SAMPLES; i++) {
        // ---- compute pass: update dd, float-track per-thread best (dist,idx) ----
        float bd = -1.0f;
        unsigned int bj = 0;
#pragma unroll
        for (int k = 0; k < PPT; k++) {
            int j = gid + k * NTOT;
            // IEEE ops in reference order; _rn intrinsics block fp-contract
            float dx = __fsub_rn(px[k], qx);
            float dy = __fsub_rn(py[k], qy);
            float dz = __fsub_rn(pz[k], qz);
            float d  = __fadd_rn(__fadd_rn(__fmul_rn(dx, dx), __fmul_rn(dy, dy)),
                                 __fmul_rn(dz, dz));
            float nd = fminf(dd[k], d);
            dd[k] = nd;
            // strict > keeps the smallest j on ties (j ascends with k)
            bool upd = (nd > bd);
            if (k == PPT - 1) upd = upd && (gid < TAIL_GID);
            bd = upd ? nd : bd;
            bj = upd ? (unsigned int)j : bj;
        }
        unsigned long long key =
            ((unsigned long long)__float_as_uint(bd) << 32) |
            (unsigned long long)(unsigned int)(N_POINTS - bj);

        // ---- per-wave reduce, stage into LDS ----
        unsigned long long wmax = wave_scan_max_u64<6, 63>(key);
        if (lane == 0) s_wmax[wid] = wmax;
        __syncthreads();

        unsigned long long* cur = slot + (size_t)(i - 1) * NBLK * EPAD;
        if (wid == 0) {
            // ---- block reduce: 8 wave maxima -> 1 entry, ONE store to a
            //      PRIVATE cache line (no other writer touches this line) ----
            unsigned long long bk = (lane < NWAVE) ? s_wmax[lane] : 0ull;
            unsigned long long blockmax = wave_scan_max_u64<3, 7>(bk);
            if (lane == 0)
                __hip_atomic_store(&cur[(size_t)bid * EPAD], blockmax,
                                   __ATOMIC_RELAXED, __HIP_MEMORY_SCOPE_AGENT);

            // ---- poll: lane l (<32) waits on entry l; 32 DISTINCT lines,
            //      fetched in parallel by the one vector load ----
            unsigned long long e = 0ull;
            if (lane < NBLK) {
                do {
                    e = __hip_atomic_load(&cur[(size_t)lane * EPAD],
                                          __ATOMIC_RELAXED,
                                          __HIP_MEMORY_SCOPE_AGENT);
                } while (e == 0ull);
            }

            // ---- speculative pivot fetch: each lane loads ITS candidate's row
            //      (issues immediately; latency overlaps the final reduce) ----
            unsigned int widx = 0;
            float4 pv = make_float4(0.f, 0.f, 0.f, 0.f);
            if (lane < NBLK) {
                widx = N_POINTS - (unsigned int)(e & 0xffffffffull);
                pv = *reinterpret_cast<const float4*>(feats + (size_t)widx * WIDTH);
            }

            unsigned long long win =
                wave_scan_max_u64<5, 31>((lane < NBLK) ? e : 0ull);

            // Exactly one lane matches (block candidates have distinct indices)
            if (lane < NBLK && e == win) {
                s_qx = pv.x; s_qy = pv.y; s_qz = pv.z;
                if (bid == 0) out[i] = (int)widx;
            }
        }
        // Waves 1..7 idle here while wave 0 runs the exchange
        __syncthreads();
        qx = s_qx; qy = s_qy; qz = s_qz;
    }
}

extern "C" void kernel_launch(void* const* d_in, const int* in_sizes, int n_in,
                              void* d_out, int out_size, void* d_ws, size_t ws_size,
                              hipStream_t stream) {
    const float* feats = (const float*)d_in[0];
    int* out = (int*)d_out;
    unsigned long long* slot = (unsigned long long*)d_ws;  // ~2 MiB used

    fps_init<<<(SLOT_WORDS + 255) / 256, 256, 0, stream>>>(slot, out);
    // 32 blocks x 512 thr: all blocks trivially co-resident
    fps_main<<<NBLK, NTHR, 0, stream>>>(feats, out, slot);
}